// Round 7
// baseline (149.310 us; speedup 1.0000x reference)
//
#include <hip/hip_runtime.h>
#include <hip/hip_bf16.h>

typedef short short8 __attribute__((ext_vector_type(8)));
typedef short short4v __attribute__((ext_vector_type(4)));
typedef float f32x4 __attribute__((ext_vector_type(4)));
typedef float f32x16 __attribute__((ext_vector_type(16)));

#define HID 4096
#define CST 68   // f32 LDS row stride for cayley kernel

__device__ __forceinline__ unsigned short f2bf(float f) {
    unsigned int u = __float_as_uint(f);
    u = (u + 0x7FFFu + ((u >> 16) & 1u)) >> 16;
    return (unsigned short)u;
}

// ---------------- BW probes (diagnostic; run before the real kernels) ----------------
__global__ __launch_bounds__(256) void probe_read(const f32x4* __restrict__ in, size_t n) {
    size_t i = (size_t)blockIdx.x * 256 + threadIdx.x;
    const size_t st = (size_t)gridDim.x * 256;
    f32x4 s = {0.f, 0.f, 0.f, 0.f};
    for (; i < n; i += st) s += in[i];
    asm volatile("" :: "v"(s[0]), "v"(s[1]), "v"(s[2]), "v"(s[3]));
}

__global__ __launch_bounds__(256) void probe_copy(const f32x4* __restrict__ in,
                                                  f32x4* __restrict__ outp, size_t n) {
    size_t i = (size_t)blockIdx.x * 256 + threadIdx.x;
    const size_t st = (size_t)gridDim.x * 256;
    for (; i < n; i += st) outp[i] = in[i];
}

// f32x4 = row i of SA (64x64, stride CST) times SB columns j0..j0+3
__device__ __forceinline__ f32x4 mm4(const float* SA, const float* SB, int i, int j0) {
    f32x4 acc = {0.f, 0.f, 0.f, 0.f};
#pragma unroll 8
    for (int k = 0; k < 64; ++k) {
        float a = SA[i * CST + k];
        acc += a * *reinterpret_cast<const f32x4*>(SB + k * CST + j0);
    }
    return acc;
}

// ---------- Kernel 1: Cayley (Neumann product form) + M-build, fused ----------
__global__ __launch_bounds__(1024) void cayley_build_kernel(
    const float* __restrict__ rul, const float* __restrict__ rvl, const float* __restrict__ dl,
    const float* __restrict__ rur, const float* __restrict__ rvr, const float* __restrict__ dr,
    const int* __restrict__ invt,
    unsigned short* __restrict__ plb, unsigned short* __restrict__ mrtb)
{
    __shared__ __align__(16) float Yw[64 * CST], Aw[64 * CST], Pw[64 * CST];
    __shared__ __align__(16) float Qw[64 * CST], QTw[64 * CST];
    __shared__ float dd[64];

    const float* ru; const float* rv; const float* dv; unsigned short* ob;
    if (blockIdx.x == 0) { ru = rul; rv = rvl; dv = dl; ob = plb; }
    else                 { ru = rur; rv = rvr; dv = dr; ob = mrtb; }

    const int tid = threadIdx.x;
    const int i = tid >> 4;
    const int j0 = (tid & 15) << 2;

    for (int pass = 0; pass < 2; ++pass) {
        const float* raw = (pass == 0) ? ru : rv;
#pragma unroll
        for (int q = 0; q < 4; ++q) {
            int j = j0 + q;
            float v = 0.f;
            if (j > i)      v =  raw[i * 64 + j];
            else if (j < i) v = -raw[j * 64 + i];
            Yw[i * CST + j] = 0.5f * v;
        }
        __syncthreads();
        f32x4 a = mm4(Yw, Yw, i, j0);                    // A = Y*Y
        __syncthreads();
        *reinterpret_cast<f32x4*>(Aw + i * CST + j0) = a;
        *reinterpret_cast<f32x4*>(Pw + i * CST + j0) =   // P = Y + A
            a + *reinterpret_cast<const f32x4*>(Yw + i * CST + j0);
        __syncthreads();
        a = mm4(Pw, Aw, i, j0);                          // P += P*A
        __syncthreads();
        *reinterpret_cast<f32x4*>(Pw + i * CST + j0) += a;
        __syncthreads();
        a = mm4(Aw, Aw, i, j0);                          // A = A*A
        __syncthreads();
        *reinterpret_cast<f32x4*>(Aw + i * CST + j0) = a;
        __syncthreads();
        a = mm4(Pw, Aw, i, j0);                          // P += P*A
        __syncthreads();
        f32x4 p = *reinterpret_cast<const f32x4*>(Pw + i * CST + j0) + a;
#pragma unroll
        for (int q = 0; q < 4; ++q) {
            int j = j0 + q;
            float qv = ((i == j) ? 1.f : 0.f) + 2.f * p[q];
            if (pass == 0) Qw[i * CST + j]  = qv;   // Qu[i][j]
            else           QTw[j * CST + i] = qv;   // Qv^T
        }
        __syncthreads();
    }
    if (tid < 64) { float d = dv[tid]; dd[tid] = (invt[0] != 0) ? (1.0f / d) : d; }
    __syncthreads();

    f32x4 m = {0.f, 0.f, 0.f, 0.f};
#pragma unroll 8
    for (int j = 0; j < 64; ++j) {
        float aa = Qw[i * CST + j] * dd[j];
        m += aa * *reinterpret_cast<const f32x4*>(QTw + j * CST + j0);
    }
#pragma unroll
    for (int q = 0; q < 4; ++q)
        ob[(j0 + q) * 64 + i] = f2bf(m[q]);
}

// ---------- Kernel 2: coalesced-I/O kron, 1 token/wave, 32x32x16 MFMA ----------
// (verbatim round-6 version: known-correct, ~90us, for clean A/B vs probes)
__global__ __launch_bounds__(256, 4) void kron_kernel(
    const float* __restrict__ inp, const float* __restrict__ ds,
    const unsigned short* __restrict__ plb, const unsigned short* __restrict__ mrtb,
    const int* __restrict__ invt, float* __restrict__ out, int ntok)
{
    __shared__ __align__(16) unsigned char sbuf[4][8192];
    const int w = threadIdx.x >> 6;
    const int lane = threadIdx.x & 63;
    const int r = lane & 31;      // row/col within 32-tile
    const int h = lane >> 5;      // k-half
    unsigned char* S = sbuf[w];

    const int t = blockIdx.x * 4 + w;
    if (t >= ntok) return;
    const bool inv = (invt[0] != 0);

    // ---- Phase A: stage token, fully coalesced (2KB contiguous per step) ----
    const float* xt = inp + (size_t)t * HID;
    const int c = lane & 7;          // chunk within row
    const int mr0 = lane >> 3;       // row within span
#pragma unroll
    for (int s = 0; s < 8; ++s) {
        const int fi = s * 512 + lane * 8;
        f32x4 x0 = *reinterpret_cast<const f32x4*>(xt + fi);
        f32x4 x1 = *reinterpret_cast<const f32x4*>(xt + fi + 4);
        f32x4 d0 = *reinterpret_cast<const f32x4*>(ds + fi);
        f32x4 d1 = *reinterpret_cast<const f32x4*>(ds + fi + 4);
        if (inv) {
#pragma unroll
            for (int e = 0; e < 4; ++e) { x0[e] /= d0[e]; x1[e] /= d1[e]; }
        } else {
            x0 *= d0; x1 *= d1;
        }
        short8 f;
#pragma unroll
        for (int e = 0; e < 4; ++e) {
            f[e]     = (short)f2bf(x0[e]);
            f[e + 4] = (short)f2bf(x1[e]);
        }
        const int m = s * 8 + mr0;
        *reinterpret_cast<short8*>(S + ((m * 8 + (c ^ (m & 7))) << 4)) = f;
    }
    asm volatile("s_waitcnt lgkmcnt(0)" ::: "memory");
    __builtin_amdgcn_sched_barrier(0);

    // ---- Phase B: A1 fragments (LDS) + B1 fragments (MR^T, L1) ----
    short8 a1[2][4];
#pragma unroll
    for (int mt = 0; mt < 2; ++mt)
#pragma unroll
        for (int kt = 0; kt < 4; ++kt)
            a1[mt][kt] = *reinterpret_cast<const short8*>(
                S + (((32 * mt + r) * 8 + ((2 * kt + h) ^ (r & 7))) << 4));
    short8 b1[4][2];
#pragma unroll
    for (int kt = 0; kt < 4; ++kt)
#pragma unroll
        for (int nt = 0; nt < 2; ++nt)
            b1[kt][nt] = *reinterpret_cast<const short8*>(
                (const short*)mrtb + (32 * nt + r) * 64 + 16 * kt + 8 * h);

    asm volatile("s_waitcnt lgkmcnt(0)" ::: "memory");
    __builtin_amdgcn_sched_barrier(0);

    // ---- mfma1 per tile, then write Z^T fragment into the same LDS tile ----
#pragma unroll
    for (int mt = 0; mt < 2; ++mt)
#pragma unroll
        for (int nt = 0; nt < 2; ++nt) {
            f32x16 acc = {0.f};
#pragma unroll
            for (int kt = 0; kt < 4; ++kt)
                acc = __builtin_amdgcn_mfma_f32_32x32x16_bf16(a1[mt][kt], b1[kt][nt], acc, 0, 0, 0);
            const int l = 32 * nt + r;
#pragma unroll
            for (int q = 0; q < 4; ++q) {
                short4v zz;
#pragma unroll
                for (int e = 0; e < 4; ++e) zz[e] = (short)f2bf(acc[4 * q + e]);
                *reinterpret_cast<short4v*>(
                    S + (((l * 8 + ((4 * mt + q) ^ (l & 7))) << 4) + 8 * h)) = zz;
            }
        }
    asm volatile("s_waitcnt lgkmcnt(0)" ::: "memory");
    __builtin_amdgcn_sched_barrier(0);

    // ---- Phase D: Out = PL * Z ----
    short8 b2[4][2];
#pragma unroll
    for (int kt = 0; kt < 4; ++kt)
#pragma unroll
        for (int nt = 0; nt < 2; ++nt)
            b2[kt][nt] = *reinterpret_cast<const short8*>(
                S + (((32 * nt + r) * 8 + ((2 * kt + h) ^ (r & 7))) << 4));
    short8 a2[2][4];
#pragma unroll
    for (int mt = 0; mt < 2; ++mt)
#pragma unroll
        for (int kt = 0; kt < 4; ++kt)
            a2[mt][kt] = *reinterpret_cast<const short8*>(
                (const short*)plb + (32 * mt + r) * 64 + 16 * kt + 8 * h);

    float* op = out + (size_t)t * HID;
#pragma unroll
    for (int mt = 0; mt < 2; ++mt)
#pragma unroll
        for (int nt = 0; nt < 2; ++nt) {
            f32x16 acc = {0.f};
#pragma unroll
            for (int kt = 0; kt < 4; ++kt)
                acc = __builtin_amdgcn_mfma_f32_32x32x16_bf16(a2[mt][kt], b2[kt][nt], acc, 0, 0, 0);
#pragma unroll
            for (int g = 0; g < 16; ++g) {
                const int k = 32 * mt + (g & 3) + 8 * (g >> 2) + 4 * h;
                op[k * 64 + 32 * nt + r] = acc[g];
            }
        }
}

extern "C" void kernel_launch(void* const* d_in, const int* in_sizes, int n_in,
                              void* d_out, int out_size, void* d_ws, size_t ws_size,
                              hipStream_t stream) {
    const float* inp = (const float*)d_in[0];
    const float* rul = (const float*)d_in[1];
    const float* rvl = (const float*)d_in[2];
    const float* dl  = (const float*)d_in[3];
    const float* rur = (const float*)d_in[4];
    const float* rvr = (const float*)d_in[5];
    const float* dr  = (const float*)d_in[6];
    const float* ds  = (const float*)d_in[7];
    const int*   invt = (const int*)d_in[8];
    float* out = (float*)d_out;

    unsigned short* plb  = (unsigned short*)d_ws;   // 4096 bf16 (PL = ML^T, row-major)
    unsigned short* mrtb = plb + 4096;              // 4096 bf16 (MR^T, row-major)

    const int ntok = in_sizes[0] / HID;
    const size_t nvec = (size_t)ntok * HID / 4;     // f32x4 elements

    // --- diagnostic probes (before the real kernels; kron overwrites out) ---
    hipLaunchKernelGGL(probe_read, dim3(2048), dim3(256), 0, stream,
                       (const f32x4*)inp, nvec);
    hipLaunchKernelGGL(probe_copy, dim3(2048), dim3(256), 0, stream,
                       (const f32x4*)inp, (f32x4*)out, nvec);

    hipLaunchKernelGGL(cayley_build_kernel, dim3(2), dim3(1024), 0, stream,
                       rul, rvl, dl, rur, rvr, dr, invt, plb, mrtb);
    const int nblk = (ntok + 3) / 4;
    hipLaunchKernelGGL(kron_kernel, dim3(nblk), dim3(256), 0, stream,
                       inp, ds, plb, mrtb, invt, out, ntok);
}

// Round 8
// 119.017 us; speedup vs baseline: 1.2545x; 1.2545x over previous
//
#include <hip/hip_runtime.h>
#include <hip/hip_bf16.h>

typedef short short8 __attribute__((ext_vector_type(8)));
typedef short short4v __attribute__((ext_vector_type(4)));
typedef float f32x4 __attribute__((ext_vector_type(4)));
typedef float f32x16 __attribute__((ext_vector_type(16)));

#define HID 4096
#define CST 68     // f32 LDS row stride for cayley kernel
#define TPW 2      // tokens per wave in kron
#define WLDS 9216  // LDS bytes per wave (8KB bf16 tile / 8.5KB padded f32 Y-half)

#define LGKM0 do { asm volatile("s_waitcnt lgkmcnt(0)" ::: "memory"); \
                   __builtin_amdgcn_sched_barrier(0); } while (0)

__device__ __forceinline__ unsigned short f2bf(float f) {
    unsigned int u = __float_as_uint(f);
    u = (u + 0x7FFFu + ((u >> 16) & 1u)) >> 16;
    return (unsigned short)u;
}

// f32x4 = row i of SA (64x64, stride CST) times SB columns j0..j0+3
__device__ __forceinline__ f32x4 mm4(const float* SA, const float* SB, int i, int j0) {
    f32x4 acc = {0.f, 0.f, 0.f, 0.f};
#pragma unroll 8
    for (int k = 0; k < 64; ++k) {
        float a = SA[i * CST + k];
        acc += a * *reinterpret_cast<const f32x4*>(SB + k * CST + j0);
    }
    return acc;
}

// ---------- Kernel 1: Cayley (Neumann product form) + M-build, fused ----------
// grid=2 (block 0: left -> plp, block 1: right -> mrp), 1024 threads.
// Q = I + 2*(Y + ... + Y^8), Y = X/2, X = triu(raw,1)-triu(raw,1)^T.
// NEW: writes tables PACKED in kron fragment order so kron's loads are
// lane-contiguous dwordx4:
//  left : plp[(( (j>>5)*4 + (i>>4) )*64 + (j&31) + 32*((i>>3)&1))*8 + (i&7)] = ML[i][j]
//  right: mrp[(( (i>>4)*2 + (j>>5) )*64 + (j&31) + 32*((i>>3)&1))*8 + (i&7)] = MR[i][j]
__global__ __launch_bounds__(1024) void cayley_build_kernel(
    const float* __restrict__ rul, const float* __restrict__ rvl, const float* __restrict__ dl,
    const float* __restrict__ rur, const float* __restrict__ rvr, const float* __restrict__ dr,
    const int* __restrict__ invt,
    unsigned short* __restrict__ plp, unsigned short* __restrict__ mrp)
{
    __shared__ __align__(16) float Yw[64 * CST], Aw[64 * CST], Pw[64 * CST];
    __shared__ __align__(16) float Qw[64 * CST], QTw[64 * CST];
    __shared__ float dd[64];

    const float* ru; const float* rv; const float* dv; unsigned short* ob;
    if (blockIdx.x == 0) { ru = rul; rv = rvl; dv = dl; ob = plp; }
    else                 { ru = rur; rv = rvr; dv = dr; ob = mrp; }

    const int tid = threadIdx.x;
    const int i = tid >> 4;
    const int j0 = (tid & 15) << 2;

    for (int pass = 0; pass < 2; ++pass) {
        const float* raw = (pass == 0) ? ru : rv;
#pragma unroll
        for (int q = 0; q < 4; ++q) {
            int j = j0 + q;
            float v = 0.f;
            if (j > i)      v =  raw[i * 64 + j];
            else if (j < i) v = -raw[j * 64 + i];
            Yw[i * CST + j] = 0.5f * v;
        }
        __syncthreads();
        f32x4 a = mm4(Yw, Yw, i, j0);                    // A = Y*Y
        __syncthreads();
        *reinterpret_cast<f32x4*>(Aw + i * CST + j0) = a;
        *reinterpret_cast<f32x4*>(Pw + i * CST + j0) =   // P = Y + A
            a + *reinterpret_cast<const f32x4*>(Yw + i * CST + j0);
        __syncthreads();
        a = mm4(Pw, Aw, i, j0);                          // P += P*A
        __syncthreads();
        *reinterpret_cast<f32x4*>(Pw + i * CST + j0) += a;
        __syncthreads();
        a = mm4(Aw, Aw, i, j0);                          // A = A*A
        __syncthreads();
        *reinterpret_cast<f32x4*>(Aw + i * CST + j0) = a;
        __syncthreads();
        a = mm4(Pw, Aw, i, j0);                          // P += P*A
        __syncthreads();
        f32x4 p = *reinterpret_cast<const f32x4*>(Pw + i * CST + j0) + a;
#pragma unroll
        for (int q = 0; q < 4; ++q) {
            int j = j0 + q;
            float qv = ((i == j) ? 1.f : 0.f) + 2.f * p[q];
            if (pass == 0) Qw[i * CST + j]  = qv;   // Qu[i][j]
            else           QTw[j * CST + i] = qv;   // Qv^T
        }
        __syncthreads();
    }
    if (tid < 64) { float d = dv[tid]; dd[tid] = (invt[0] != 0) ? (1.0f / d) : d; }
    __syncthreads();

    // M[i][j0+q] = sum_j Qu[i][j]*dd[j]*QvT[j][j0+q]
    f32x4 m = {0.f, 0.f, 0.f, 0.f};
#pragma unroll 8
    for (int j = 0; j < 64; ++j) {
        float aa = Qw[i * CST + j] * dd[j];
        m += aa * *reinterpret_cast<const f32x4*>(QTw + j * CST + j0);
    }
    const int kt = i >> 4, hh = (i >> 3) & 1, e = i & 7;
#pragma unroll
    for (int q = 0; q < 4; ++q) {
        int j = j0 + q;
        unsigned short v = f2bf(m[q]);
        int dst;
        if (blockIdx.x == 0)
            dst = (((j >> 5) * 4 + kt) * 64 + (j & 31) + 32 * hh) * 8 + e;
        else
            dst = ((kt * 2 + (j >> 5)) * 64 + (j & 31) + 32 * hh) * 8 + e;
        ob[dst] = v;
    }
}

// ---------- Kernel 2: all-contiguous fused kron ----------
// 1 token/wave/iter, TPW-token loop, wave-private LDS (no barriers).
// Phase A: contiguous loads -> (x*ds) -> swizzled bf16 Xs tile.
// Phase B: Z = Xs*MR (A-frags from LDS, B-frags = packed table, contiguous).
// Phase C: Zt = Z^T into same tile (b64 writes).
// Phase D: Y = PL*Z (A = packed table, B from LDS); Y tiles -> padded f32 LDS
//          (XOR-swizzled) -> lane-linear b128 reads -> 16 fully-contiguous
//          1KB global stores per token.
__global__ __launch_bounds__(256, 4) void kron_kernel(
    const float* __restrict__ inp, const float* __restrict__ ds,
    const unsigned short* __restrict__ plp, const unsigned short* __restrict__ mrp,
    const int* __restrict__ invt, float* __restrict__ out, int ntok)
{
    __shared__ __align__(16) unsigned char sbuf[4][WLDS];
    const int w = threadIdx.x >> 6;
    const int lane = threadIdx.x & 63;
    const int r = lane & 31;
    const int h = lane >> 5;
    unsigned char* S = sbuf[w];
    float* SF = reinterpret_cast<float*>(S);
    const bool inv = (invt[0] != 0);

    const int t0 = (blockIdx.x * 4 + w) * TPW;
#pragma unroll
    for (int it = 0; it < TPW; ++it) {
        const int t = t0 + it;
        if (t >= ntok) break;
        const float* xt = inp + (size_t)t * HID;

        // ---- Phase A: stage Xs (contiguous 2KB per chunk-pair across wave) ----
#pragma unroll
        for (int s = 0; s < 8; ++s) {
            const int fi = s * 512 + lane * 8;
            f32x4 x0 = *reinterpret_cast<const f32x4*>(xt + fi);
            f32x4 x1 = *reinterpret_cast<const f32x4*>(xt + fi + 4);
            f32x4 d0 = *reinterpret_cast<const f32x4*>(ds + fi);
            f32x4 d1 = *reinterpret_cast<const f32x4*>(ds + fi + 4);
            if (inv) {
#pragma unroll
                for (int e = 0; e < 4; ++e) { x0[e] /= d0[e]; x1[e] /= d1[e]; }
            } else {
                x0 *= d0; x1 *= d1;
            }
            short8 f;
#pragma unroll
            for (int e = 0; e < 4; ++e) {
                f[e]     = (short)f2bf(x0[e]);
                f[e + 4] = (short)f2bf(x1[e]);
            }
            const int m = s * 8 + (lane >> 3);
            const int c = lane & 7;
            *reinterpret_cast<short8*>(S + ((m * 8 + (c ^ (m & 7))) << 4)) = f;
        }
        LGKM0;

        // ---- Phase B: Z = Xs * MR ----
        short8 a1[8];
#pragma unroll
        for (int mt = 0; mt < 2; ++mt)
#pragma unroll
            for (int kt = 0; kt < 4; ++kt)
                a1[mt * 4 + kt] = *reinterpret_cast<const short8*>(
                    S + (((32 * mt + r) * 8 + ((2 * kt + h) ^ (r & 7))) << 4));
        short8 b1[8];
#pragma unroll
        for (int kt = 0; kt < 4; ++kt)
#pragma unroll
            for (int nt = 0; nt < 2; ++nt)
                b1[kt * 2 + nt] = *reinterpret_cast<const short8*>(
                    mrp + ((kt * 2 + nt) * 64 + lane) * 8);
        LGKM0;   // a1 landed; Xs tile free for Zt overwrite

#pragma unroll
        for (int mt = 0; mt < 2; ++mt)
#pragma unroll
            for (int nt = 0; nt < 2; ++nt) {
                f32x16 acc = {0.f};
#pragma unroll
                for (int kt = 0; kt < 4; ++kt)
                    acc = __builtin_amdgcn_mfma_f32_32x32x16_bf16(
                        a1[mt * 4 + kt], b1[kt * 2 + nt], acc, 0, 0, 0);
                const int l2 = 32 * nt + r;
#pragma unroll
                for (int q = 0; q < 4; ++q) {
                    short4v zz;
#pragma unroll
                    for (int e = 0; e < 4; ++e) zz[e] = (short)f2bf(acc[4 * q + e]);
                    *reinterpret_cast<short4v*>(
                        S + (((l2 * 8 + ((4 * mt + q) ^ (l2 & 7))) << 4) + 8 * h)) = zz;
                }
            }
        LGKM0;

        // ---- Phase D: Y = PL * Z ----
        short8 b2[8];
#pragma unroll
        for (int kt = 0; kt < 4; ++kt)
#pragma unroll
            for (int nt = 0; nt < 2; ++nt)
                b2[kt * 2 + nt] = *reinterpret_cast<const short8*>(
                    S + (((32 * nt + r) * 8 + ((2 * kt + h) ^ (r & 7))) << 4));
        short8 a2[8];
#pragma unroll
        for (int mt = 0; mt < 2; ++mt)
#pragma unroll
            for (int kt = 0; kt < 4; ++kt)
                a2[mt * 4 + kt] = *reinterpret_cast<const short8*>(
                    plp + ((mt * 4 + kt) * 64 + lane) * 8);
        LGKM0;   // b2 landed; tile free for f32 Y-half

        float* op = out + (size_t)t * HID;
#pragma unroll
        for (int mt = 0; mt < 2; ++mt) {
#pragma unroll
            for (int nt = 0; nt < 2; ++nt) {
                f32x16 acc = {0.f};
#pragma unroll
                for (int kt = 0; kt < 4; ++kt)
                    acc = __builtin_amdgcn_mfma_f32_32x32x16_bf16(
                        a2[mt * 4 + kt], b2[kt * 2 + nt], acc, 0, 0, 0);
#pragma unroll
                for (int g = 0; g < 16; ++g) {
                    const int rr = (g & 3) + 8 * (g >> 2) + 4 * h;   // 0..31
                    const int cy = 32 * nt + r;
                    SF[rr * 68 + (cy ^ ((rr & 7) << 2))] = acc[g];
                }
            }
            LGKM0;   // Y-half fully written
#pragma unroll
            for (int s = 0; s < 8; ++s) {
                const int ro = s * 4 + (lane >> 4);
                const int c0 = (lane & 15) * 4;
                f32x4 y = *reinterpret_cast<const f32x4*>(
                    SF + ro * 68 + (c0 ^ ((ro & 7) << 2)));
                *reinterpret_cast<f32x4*>(op + (32 * mt + ro) * 64 + c0) = y;
            }
            LGKM0;   // reads landed before half-1 / next-token writes
        }
    }
}

extern "C" void kernel_launch(void* const* d_in, const int* in_sizes, int n_in,
                              void* d_out, int out_size, void* d_ws, size_t ws_size,
                              hipStream_t stream) {
    const float* inp = (const float*)d_in[0];
    const float* rul = (const float*)d_in[1];
    const float* rvl = (const float*)d_in[2];
    const float* dl  = (const float*)d_in[3];
    const float* rur = (const float*)d_in[4];
    const float* rvr = (const float*)d_in[5];
    const float* dr  = (const float*)d_in[6];
    const float* ds  = (const float*)d_in[7];
    const int*   invt = (const int*)d_in[8];
    float* out = (float*)d_out;

    unsigned short* plp = (unsigned short*)d_ws;   // 4096 bf16, fragment-packed PL
    unsigned short* mrp = plp + 4096;              // 4096 bf16, fragment-packed MR

    const int ntok = in_sizes[0] / HID;

    hipLaunchKernelGGL(cayley_build_kernel, dim3(2), dim3(1024), 0, stream,
                       rul, rvl, dl, rur, rvr, dr, invt, plp, mrp);
    const int nblk = (ntok + 4 * TPW - 1) / (4 * TPW);
    hipLaunchKernelGGL(kron_kernel, dim3(nblk), dim3(256), 0, stream,
                       inp, ds, plp, mrp, invt, out, ntok);
}

// Round 10
// 83.433 us; speedup vs baseline: 1.7896x; 1.4265x over previous
//
#include <hip/hip_runtime.h>
#include <hip/hip_bf16.h>

typedef short short8 __attribute__((ext_vector_type(8)));
typedef float f32x4 __attribute__((ext_vector_type(4)));
typedef float f32x16 __attribute__((ext_vector_type(16)));
typedef unsigned int u32x4 __attribute__((ext_vector_type(4)));

#define HID 4096
#define CST 68     // f32 LDS row stride for cayley kernel

#define LGKM0 do { asm volatile("s_waitcnt lgkmcnt(0)" ::: "memory"); \
                   __builtin_amdgcn_sched_barrier(0); } while (0)

__device__ __forceinline__ unsigned short f2bf(float f) {
    unsigned int u = __float_as_uint(f);
    u = (u + 0x7FFFu + ((u >> 16) & 1u)) >> 16;
    return (unsigned short)u;
}

// f32x4 = row i of SA (64x64, stride CST) times SB columns j0..j0+3
__device__ __forceinline__ f32x4 mm4(const float* SA, const float* SB, int i, int j0) {
    f32x4 acc = {0.f, 0.f, 0.f, 0.f};
#pragma unroll 8
    for (int k = 0; k < 64; ++k) {
        float a = SA[i * CST + k];
        acc += a * *reinterpret_cast<const f32x4*>(SB + k * CST + j0);
    }
    return acc;
}

// ---------- Kernel 1: Cayley (Neumann product form) + M-build, fused ----------
// grid=2 (block 0: left -> plp, block 1: right -> mrp), 1024 threads.
// Writes tables PACKED in kron 32x32x16-fragment order (verified round 8):
//  left : plp[(((j>>5)*4 + (i>>4))*64 + (j&31) + 32*((i>>3)&1))*8 + (i&7)] = ML[i][j]
//  right: mrp[(((i>>4)*2 + (j>>5))*64 + (j&31) + 32*((i>>3)&1))*8 + (i&7)] = MR[i][j]
__global__ __launch_bounds__(1024) void cayley_build_kernel(
    const float* __restrict__ rul, const float* __restrict__ rvl, const float* __restrict__ dl,
    const float* __restrict__ rur, const float* __restrict__ rvr, const float* __restrict__ dr,
    const int* __restrict__ invt,
    unsigned short* __restrict__ plp, unsigned short* __restrict__ mrp)
{
    __shared__ __align__(16) float Yw[64 * CST], Aw[64 * CST], Pw[64 * CST];
    __shared__ __align__(16) float Qw[64 * CST], QTw[64 * CST];
    __shared__ float dd[64];

    const float* ru; const float* rv; const float* dv; unsigned short* ob;
    if (blockIdx.x == 0) { ru = rul; rv = rvl; dv = dl; ob = plp; }
    else                 { ru = rur; rv = rvr; dv = dr; ob = mrp; }

    const int tid = threadIdx.x;
    const int i = tid >> 4;
    const int j0 = (tid & 15) << 2;

    for (int pass = 0; pass < 2; ++pass) {
        const float* raw = (pass == 0) ? ru : rv;
#pragma unroll
        for (int q = 0; q < 4; ++q) {
            int j = j0 + q;
            float v = 0.f;
            if (j > i)      v =  raw[i * 64 + j];
            else if (j < i) v = -raw[j * 64 + i];
            Yw[i * CST + j] = 0.5f * v;
        }
        __syncthreads();
        f32x4 a = mm4(Yw, Yw, i, j0);                    // A = Y*Y
        __syncthreads();
        *reinterpret_cast<f32x4*>(Aw + i * CST + j0) = a;
        *reinterpret_cast<f32x4*>(Pw + i * CST + j0) =   // P = Y + A
            a + *reinterpret_cast<const f32x4*>(Yw + i * CST + j0);
        __syncthreads();
        a = mm4(Pw, Aw, i, j0);                          // P += P*A
        __syncthreads();
        *reinterpret_cast<f32x4*>(Pw + i * CST + j0) += a;
        __syncthreads();
        a = mm4(Aw, Aw, i, j0);                          // A = A*A
        __syncthreads();
        *reinterpret_cast<f32x4*>(Aw + i * CST + j0) = a;
        __syncthreads();
        a = mm4(Pw, Aw, i, j0);                          // P += P*A
        __syncthreads();
        f32x4 p = *reinterpret_cast<const f32x4*>(Pw + i * CST + j0) + a;
#pragma unroll
        for (int q = 0; q < 4; ++q) {
            int j = j0 + q;
            float qv = ((i == j) ? 1.f : 0.f) + 2.f * p[q];
            if (pass == 0) Qw[i * CST + j]  = qv;   // Qu[i][j]
            else           QTw[j * CST + i] = qv;   // Qv^T
        }
        __syncthreads();
    }
    if (tid < 64) { float d = dv[tid]; dd[tid] = (invt[0] != 0) ? (1.0f / d) : d; }
    __syncthreads();

    // M[i][j0+q] = sum_j Qu[i][j]*dd[j]*QvT[j][j0+q]
    f32x4 m = {0.f, 0.f, 0.f, 0.f};
#pragma unroll 8
    for (int j = 0; j < 64; ++j) {
        float aa = Qw[i * CST + j] * dd[j];
        m += aa * *reinterpret_cast<const f32x4*>(QTw + j * CST + j0);
    }
    const int kt = i >> 4, hh = (i >> 3) & 1, e = i & 7;
#pragma unroll
    for (int q = 0; q < 4; ++q) {
        int j = j0 + q;
        unsigned short v = f2bf(m[q]);
        int dst;
        if (blockIdx.x == 0)
            dst = (((j >> 5) * 4 + kt) * 64 + (j & 31) + 32 * hh) * 8 + e;
        else
            dst = ((kt * 2 + (j >> 5)) * 64 + (j & 31) + 32 * hh) * 8 + e;
        ob[dst] = v;
    }
}

// ---------- Kernel 2: LDS-minimal kron, in-register Z handoff ----------
// 1 token/wave, 4 waves/block, wave-private 8KB X tile, no barriers.
// Phase A: contiguous loads -> (x*ds) -> f2bf -> swizzled LDS tile (r6-verified).
// Phase B: mfma1 Z = Xs*MR (A from LDS, B = packed table).
// Phase C: Z -> bf16 pairs (f2bf bit-ops), redistribute across the lane/lane+32
//          boundary with __builtin_amdgcn_permlane32_swap (guide T12 recipe;
//          result[0] = {lanes0-31: arg0.lo-lanes, lanes32-63: arg1.lo-lanes},
//          result[1] = {arg0.hi-lanes, arg1.hi-lanes}) so Z feeds mfma2's B
//          operand directly — NO mid-kernel LDS round-trip.
// Phase D: mfma2 Y = PL*Z (A = packed table); direct C-layout stores
//          (2 full 128B lines per store instruction; clean WRITE_SIZE in r6).
__global__ __launch_bounds__(256, 4) void kron_kernel(
    const float* __restrict__ inp, const float* __restrict__ ds,
    const unsigned short* __restrict__ plp, const unsigned short* __restrict__ mrp,
    const int* __restrict__ invt, float* __restrict__ out, int ntok)
{
    __shared__ __align__(16) unsigned char sbuf[4][8192];
    const int w = threadIdx.x >> 6;
    const int lane = threadIdx.x & 63;
    const int r = lane & 31;
    const int h = lane >> 5;
    unsigned char* S = sbuf[w];

    const int t = blockIdx.x * 4 + w;
    if (t >= ntok) return;
    const bool inv = (invt[0] != 0);
    const float* xt = inp + (size_t)t * HID;

    // ---- Phase A: stage Xs (contiguous 2KB per load pair across the wave) ----
#pragma unroll
    for (int s = 0; s < 8; ++s) {
        const int fi = s * 512 + lane * 8;
        f32x4 x0 = *reinterpret_cast<const f32x4*>(xt + fi);
        f32x4 x1 = *reinterpret_cast<const f32x4*>(xt + fi + 4);
        f32x4 d0 = *reinterpret_cast<const f32x4*>(ds + fi);
        f32x4 d1 = *reinterpret_cast<const f32x4*>(ds + fi + 4);
        if (inv) {
#pragma unroll
            for (int e = 0; e < 4; ++e) { x0[e] /= d0[e]; x1[e] /= d1[e]; }
        } else {
            x0 *= d0; x1 *= d1;
        }
        short8 f;
#pragma unroll
        for (int e = 0; e < 4; ++e) {
            f[e]     = (short)f2bf(x0[e]);
            f[e + 4] = (short)f2bf(x1[e]);
        }
        const int m = s * 8 + (lane >> 3);
        const int c = lane & 7;
        *reinterpret_cast<short8*>(S + ((m * 8 + (c ^ (m & 7))) << 4)) = f;
    }
    LGKM0;

    // ---- Phase B+C: mfma1 per tile, pack + permlane swap into zs ----
    // zs[tile = mt*2+nt][8]: post-swap packed bf16 B-words; mfma2 B-frag
    // [kt2][nt2] = zs[(kt2>>1)*2 + nt2][(kt2&1)*4 + 0..3]
    unsigned int zs[4][8];
#pragma unroll
    for (int nt = 0; nt < 2; ++nt) {
        short8 b1[4];
#pragma unroll
        for (int kt = 0; kt < 4; ++kt)
            b1[kt] = *reinterpret_cast<const short8*>(
                mrp + ((kt * 2 + nt) * 64 + lane) * 8);
#pragma unroll
        for (int mt = 0; mt < 2; ++mt) {
            short8 a1[4];
#pragma unroll
            for (int kt = 0; kt < 4; ++kt)
                a1[kt] = *reinterpret_cast<const short8*>(
                    S + (((32 * mt + r) * 8 + ((2 * kt + h) ^ (r & 7))) << 4));
            f32x16 acc = {0.f};
#pragma unroll
            for (int kt = 0; kt < 4; ++kt)
                acc = __builtin_amdgcn_mfma_f32_32x32x16_bf16(a1[kt], b1[kt], acc, 0, 0, 0);
            // pack row-pairs: q[p] = bf16(acc[2p]) | bf16(acc[2p+1])<<16
            unsigned int q[8];
#pragma unroll
            for (int p = 0; p < 8; ++p)
                q[p] = (unsigned int)f2bf(acc[2 * p]) |
                       ((unsigned int)f2bf(acc[2 * p + 1]) << 16);
            // lane/lane+32 exchange (builtin, m214-verified convention):
            //   res[0] = [arg0.lanes0-31 | arg1.lanes0-31]
            //   res[1] = [arg0.lanes32-63 | arg1.lanes32-63]
            auto s02 = __builtin_amdgcn_permlane32_swap(q[0], q[2], false, false);
            auto s13 = __builtin_amdgcn_permlane32_swap(q[1], q[3], false, false);
            auto s46 = __builtin_amdgcn_permlane32_swap(q[4], q[6], false, false);
            auto s57 = __builtin_amdgcn_permlane32_swap(q[5], q[7], false, false);
            unsigned int* z = zs[mt * 2 + nt];
            z[0] = s02[0]; z[1] = s13[0]; z[2] = s02[1]; z[3] = s13[1];
            z[4] = s46[0]; z[5] = s57[0]; z[6] = s46[1]; z[7] = s57[1];
        }
    }

    // ---- Phase D: mfma2 Y = PL * Z; direct C-layout stores ----
    float* op = out + (size_t)t * HID;
#pragma unroll
    for (int mt2 = 0; mt2 < 2; ++mt2) {
        short8 a2[4];
#pragma unroll
        for (int kt = 0; kt < 4; ++kt)
            a2[kt] = *reinterpret_cast<const short8*>(
                plp + ((mt2 * 4 + kt) * 64 + lane) * 8);
#pragma unroll
        for (int nt2 = 0; nt2 < 2; ++nt2) {
            f32x16 y = {0.f};
#pragma unroll
            for (int kt2 = 0; kt2 < 4; ++kt2) {
                const unsigned int* z = zs[(kt2 >> 1) * 2 + nt2];
                const int kb = (kt2 & 1) * 4;
                union { u32x4 u; short8 s; } cv;
                cv.u[0] = z[kb + 0]; cv.u[1] = z[kb + 1];
                cv.u[2] = z[kb + 2]; cv.u[3] = z[kb + 3];
                y = __builtin_amdgcn_mfma_f32_32x32x16_bf16(a2[kt2], cv.s, y, 0, 0, 0);
            }
#pragma unroll
            for (int g = 0; g < 16; ++g) {
                const int k = 32 * mt2 + (g & 3) + 8 * (g >> 2) + 4 * h;
                op[k * 64 + 32 * nt2 + r] = y[g];
            }
        }
    }
}

extern "C" void kernel_launch(void* const* d_in, const int* in_sizes, int n_in,
                              void* d_out, int out_size, void* d_ws, size_t ws_size,
                              hipStream_t stream) {
    const float* inp = (const float*)d_in[0];
    const float* rul = (const float*)d_in[1];
    const float* rvl = (const float*)d_in[2];
    const float* dl  = (const float*)d_in[3];
    const float* rur = (const float*)d_in[4];
    const float* rvr = (const float*)d_in[5];
    const float* dr  = (const float*)d_in[6];
    const float* ds  = (const float*)d_in[7];
    const int*   invt = (const int*)d_in[8];
    float* out = (float*)d_out;

    unsigned short* plp = (unsigned short*)d_ws;   // 4096 bf16, fragment-packed PL
    unsigned short* mrp = plp + 4096;              // 4096 bf16, fragment-packed MR

    const int ntok = in_sizes[0] / HID;

    hipLaunchKernelGGL(cayley_build_kernel, dim3(2), dim3(1024), 0, stream,
                       rul, rvl, dl, rur, rvr, dr, invt, plp, mrp);
    const int nblk = (ntok + 3) / 4;
    hipLaunchKernelGGL(kron_kernel, dim3(nblk), dim3(256), 0, stream,
                       inp, ds, plp, mrp, invt, out, ntok);
}